// Round 1
// baseline (4048.241 us; speedup 1.0000x reference)
//
#include <hip/hip_runtime.h>

// WindowAttention fused kernel, fp32 baseline.
// One block per window (4096 blocks x 256 threads).
// Per head h: qkv GEMM (LDS-staged, transposed) -> scores+softmax (regs) ->
// P@V (butterfly reduce) -> proj accumulation into persistent registers.
// LDS total 64512 B (<64KB -> 2 blocks/CU with __launch_bounds__(256,2)).

constexpr int NT   = 64;    // tokens per window
constexpr int DIMC = 192;   // channels
constexpr int NH   = 6;     // heads
constexpr float SC = 0.17677669529663687f;  // 32^-0.5

__global__ __launch_bounds__(256, 2)
void win_attn_kernel(const float* __restrict__ x,       // (B,64,192)
                     const float* __restrict__ qkv_w,   // (576,192)
                     const float* __restrict__ qkv_b,   // (576)
                     const float* __restrict__ proj_w,  // (192,192)
                     const float* __restrict__ proj_b,  // (192)
                     const float* __restrict__ rpb,     // (225,6)
                     const int*   __restrict__ ridx,    // (64,64)
                     float* __restrict__ out)           // (B,64,192)
{
  // region1: wt[48][96] (qkv weight chunk, [i][r]) OR pw_t[32][192] ([c][o])
  __shared__ float reg1[32 * 192];           // 24576 B
  // region2: xt[48][64] (x chunk, [i][t]) OR ao_t[32][64] ([dd][t])
  __shared__ float reg2[48 * 64];            // 12288 B
  __shared__ float qs[64 * 36];              // q (scaled), stride 36
  __shared__ float ks[64 * 36];
  __shared__ float vs[64 * 36];              // 3*9216 = 27648 B; total 64512 B

  const int tid = threadIdx.x;
  const int w   = blockIdx.x;
  const float* xw  = x   + (size_t)w * (NT * DIMC);
  float*       outw = out + (size_t)w * (NT * DIMC);

  // stage A map: 16 channel-groups (6 ch) x 16 token-groups (4 tok)
  const int cg  = tid >> 4;         // c0 = 6*cg
  const int tgA = tid & 15;         // t0 = 4*tgA
  // stage B/C map: 64 tokens x 4 lanes
  const int tB = tid >> 2;
  const int jB = tid & 3;
  // stage D map: 16 out-groups (12 o) x 16 token-groups (4 tok)
  const int ogD = tid >> 4;
  const int tgD = tid & 15;

  // hoisted relative-position gather indices (pre-multiplied by NH)
  int idxv[16];
  #pragma unroll
  for (int mm = 0; mm < 16; ++mm)
    idxv[mm] = ridx[tB * 64 + jB + 4 * mm] * NH;

  float oacc[4][12];
  #pragma unroll
  for (int tt = 0; tt < 4; ++tt)
    #pragma unroll
    for (int oo = 0; oo < 12; ++oo) oacc[tt][oo] = 0.f;

  for (int h = 0; h < NH; ++h) {
    // ================= stage A: qkv for head h =================
    float acc[6][4];
    #pragma unroll
    for (int cc = 0; cc < 6; ++cc)
      #pragma unroll
      for (int tt = 0; tt < 4; ++tt) acc[cc][tt] = 0.f;

    for (int i0 = 0; i0 < DIMC; i0 += 48) {
      __syncthreads();   // guard reg1/reg2 rewrite vs previous consumers
      // xt[ii][t] <- x[t][i0+ii]   (t fast in lanes -> conflict-free LDS write)
      #pragma unroll
      for (int k = 0; k < 12; ++k) {
        int flat = k * 256 + tid;
        int t = flat & 63, ii = flat >> 6;
        reg2[ii * 64 + t] = xw[t * DIMC + i0 + ii];
      }
      // wt[ii][rr] <- qkv_w[row(rr)][i0+ii], rows for head h: q,k,v blocks of 32
      #pragma unroll
      for (int k = 0; k < 18; ++k) {
        int flat = k * 256 + tid;
        int rr = flat % 96, ii = flat / 96;
        int seg = rr >> 5, lc = rr & 31;
        int grow = seg * 192 + h * 32 + lc;
        reg1[ii * 96 + rr] = qkv_w[grow * DIMC + i0 + ii];
      }
      __syncthreads();
      #pragma unroll 2
      for (int i = 0; i < 48; ++i) {
        float4 x4 = *(const float4*)(&reg2[i * 64 + 4 * tgA]);
        const float* wr = &reg1[i * 96 + 6 * cg];
        float2 w0 = *(const float2*)(wr + 0);
        float2 w1 = *(const float2*)(wr + 2);
        float2 w2 = *(const float2*)(wr + 4);
        float xa[4] = {x4.x, x4.y, x4.z, x4.w};
        float wa[6] = {w0.x, w0.y, w1.x, w1.y, w2.x, w2.y};
        #pragma unroll
        for (int cc = 0; cc < 6; ++cc)
          #pragma unroll
          for (int tt = 0; tt < 4; ++tt)
            acc[cc][tt] = fmaf(wa[cc], xa[tt], acc[cc][tt]);
      }
    }
    // scatter q/k/v (+bias, q scaled)
    #pragma unroll
    for (int cc = 0; cc < 6; ++cc) {
      int c = 6 * cg + cc;
      int seg = c >> 5, lc = c & 31;
      float bv = qkv_b[seg * 192 + h * 32 + lc];
      if (seg == 0) {
        #pragma unroll
        for (int tt = 0; tt < 4; ++tt)
          qs[(4 * tgA + tt) * 36 + lc] = (acc[cc][tt] + bv) * SC;
      } else if (seg == 1) {
        #pragma unroll
        for (int tt = 0; tt < 4; ++tt)
          ks[(4 * tgA + tt) * 36 + lc] = acc[cc][tt] + bv;
      } else {
        #pragma unroll
        for (int tt = 0; tt < 4; ++tt)
          vs[(4 * tgA + tt) * 36 + lc] = acc[cc][tt] + bv;
      }
    }
    __syncthreads();   // S1: qkv visible; reg1 free

    // prefetch pw_t[c][o] <- proj_w[o][32h+c] (overlaps with stages B/C)
    #pragma unroll
    for (int k = 0; k < 24; ++k) {
      int flat = k * 256 + tid;
      int o = flat % 192, c = flat / 192;
      reg1[c * 192 + o] = proj_w[o * DIMC + h * 32 + c];
    }

    // ================= stage B: scores + softmax =================
    float qr[32];
    {
      const float* qrow = &qs[tB * 36];
      #pragma unroll
      for (int d4 = 0; d4 < 8; ++d4) {
        float4 q4 = *(const float4*)(qrow + 4 * d4);
        qr[4*d4+0] = q4.x; qr[4*d4+1] = q4.y; qr[4*d4+2] = q4.z; qr[4*d4+3] = q4.w;
      }
    }
    float sv[16];
    #pragma unroll
    for (int mm = 0; mm < 16; ++mm) {
      const float* krow = &ks[(jB + 4 * mm) * 36];
      float a = rpb[idxv[mm] + h];
      #pragma unroll
      for (int d4 = 0; d4 < 8; ++d4) {
        float4 k4 = *(const float4*)(krow + 4 * d4);
        a = fmaf(qr[4*d4+0], k4.x, a);
        a = fmaf(qr[4*d4+1], k4.y, a);
        a = fmaf(qr[4*d4+2], k4.z, a);
        a = fmaf(qr[4*d4+3], k4.w, a);
      }
      sv[mm] = a;
    }
    float mx = sv[0];
    #pragma unroll
    for (int mm = 1; mm < 16; ++mm) mx = fmaxf(mx, sv[mm]);
    mx = fmaxf(mx, __shfl_xor(mx, 1));
    mx = fmaxf(mx, __shfl_xor(mx, 2));
    float sum = 0.f;
    #pragma unroll
    for (int mm = 0; mm < 16; ++mm) { sv[mm] = __expf(sv[mm] - mx); sum += sv[mm]; }
    sum += __shfl_xor(sum, 1);
    sum += __shfl_xor(sum, 2);
    const float inv = 1.f / sum;

    // ================= stage C: P @ V =================
    float part[32];
    #pragma unroll
    for (int dd = 0; dd < 32; ++dd) part[dd] = 0.f;
    #pragma unroll
    for (int mm = 0; mm < 16; ++mm) {
      float p = sv[mm] * inv;
      const float* vrow = &vs[(jB + 4 * mm) * 36];
      #pragma unroll
      for (int d4 = 0; d4 < 8; ++d4) {
        float4 v4 = *(const float4*)(vrow + 4 * d4);
        part[4*d4+0] = fmaf(p, v4.x, part[4*d4+0]);
        part[4*d4+1] = fmaf(p, v4.y, part[4*d4+1]);
        part[4*d4+2] = fmaf(p, v4.z, part[4*d4+2]);
        part[4*d4+3] = fmaf(p, v4.w, part[4*d4+3]);
      }
    }
    // butterfly reduce-scatter over the 4 jB lanes
    float p16[16];
    {
      const bool hi = (jB & 1);
      #pragma unroll
      for (int k2 = 0; k2 < 16; ++k2) {
        float lo_v = part[k2], hi_v = part[16 + k2];
        float sendv = hi ? lo_v : hi_v;
        float keepv = hi ? hi_v : lo_v;
        float got = __shfl_xor(sendv, 1);
        p16[k2] = keepv + got;
      }
    }
    float p8[8];
    {
      const bool hi = (jB & 2);
      #pragma unroll
      for (int k2 = 0; k2 < 8; ++k2) {
        float lo_v = p16[k2], hi_v = p16[8 + k2];
        float sendv = hi ? lo_v : hi_v;
        float keepv = hi ? hi_v : lo_v;
        float got = __shfl_xor(sendv, 2);
        p8[k2] = keepv + got;
      }
    }
    const int dd0 = (jB & 1) * 16 + (jB & 2) * 4;
    #pragma unroll
    for (int k2 = 0; k2 < 8; ++k2)
      reg2[(dd0 + k2) * 64 + tB] = p8[k2];    // ao_t[dd][t]

    __syncthreads();   // S2: ao_t + pw_t visible

    // ================= stage D: proj accumulation =================
    {
      const int o0 = 12 * ogD, t0 = 4 * tgD;
      #pragma unroll 2
      for (int c = 0; c < 32; ++c) {
        float4 a4 = *(const float4*)(&reg2[c * 64 + t0]);
        const float* pr = &reg1[c * 192 + o0];
        float4 b0 = *(const float4*)(pr + 0);
        float4 b1 = *(const float4*)(pr + 4);
        float4 b2 = *(const float4*)(pr + 8);
        float av[4]  = {a4.x, a4.y, a4.z, a4.w};
        float bw[12] = {b0.x, b0.y, b0.z, b0.w, b1.x, b1.y, b1.z, b1.w,
                        b2.x, b2.y, b2.z, b2.w};
        #pragma unroll
        for (int tt = 0; tt < 4; ++tt)
          #pragma unroll
          for (int oo = 0; oo < 12; ++oo)
            oacc[tt][oo] = fmaf(av[tt], bw[oo], oacc[tt][oo]);
      }
    }
  }

  // ================= epilogue =================
  {
    const int o0 = 12 * ogD, t0 = 4 * tgD;
    #pragma unroll
    for (int oo = 0; oo < 12; ++oo) {
      float pb = proj_b[o0 + oo];
      #pragma unroll
      for (int tt = 0; tt < 4; ++tt)
        outw[(size_t)(t0 + tt) * DIMC + o0 + oo] = oacc[tt][oo] + pb;
    }
  }
}

extern "C" void kernel_launch(void* const* d_in, const int* in_sizes, int n_in,
                              void* d_out, int out_size, void* d_ws, size_t ws_size,
                              hipStream_t stream) {
  const float* x      = (const float*)d_in[0];
  const float* qkv_w  = (const float*)d_in[1];
  const float* qkv_b  = (const float*)d_in[2];
  const float* proj_w = (const float*)d_in[3];
  const float* proj_b = (const float*)d_in[4];
  const float* rpb    = (const float*)d_in[5];
  const int*   ridx   = (const int*)d_in[6];
  float* out = (float*)d_out;
  const int B = in_sizes[0] / (NT * DIMC);   // 4096 windows
  hipLaunchKernelGGL(win_attn_kernel, dim3(B), dim3(256), 0, stream,
                     x, qkv_w, qkv_b, proj_w, proj_b, rpb, ridx, out);
}